// Round 6
// baseline (266.004 us; speedup 1.0000x reference)
//
#include <hip/hip_runtime.h>
#include <math.h>

// ConvolutionalCapsule EM routing, fused, one block per output position.
// R6 = R5 with the double-Kc bug fixed: lp starts at 0 and Kc is added once
// AFTER the cross-rhalf shfl combine (R5 added Kc in both halves -> logits
// were 2*Kc + S, breaking the softmax; absmax 1.375 vs 0.25).
// R5 design: thread t = isub*64 + rhalf*32 + c; each thread owns 8 of 16 pose
// dims -> per-thread state fits the 64-VGPR budget the compiler pins for
// 1024-thread workgroups (R2-R4 spilled 47MB at VGPR=64).

#define EPSF 1e-7f
#define KKI 288
#define NC 32
#define NTHREADS 1024
#define NSUB 16        // isub count
#define IPT 18         // KKI/NSUB

__device__ __forceinline__ float frcp(float x) { return __builtin_amdgcn_rcpf(x); }

__global__ __launch_bounds__(NTHREADS)
void caps_em_kernel(const float* __restrict__ x, const float* __restrict__ Wg,
                    const float* __restrict__ beta_v, const float* __restrict__ beta_a,
                    float* __restrict__ out)
{
    __shared__ __attribute__((aligned(16))) float MpL[KKI * 16];  // patch poses
    __shared__ float apL[KKI];        // patch activations
    __shared__ float T1L[NC * 18];    // sum_i Rw*v (stride 18)
    __shared__ float S1L[NC * 18];    // sum_i v
    __shared__ float S2L[NC * 18];    // sum_i v^2
    __shared__ float RsumL[NC];
    __shared__ float ML[NC * 18];     // M
    __shared__ __attribute__((aligned(16))) float ABL[NC * 36];   // {A,B} interleaved
    __shared__ float constL[NC];      // Kc (includes -sum A*M^2)
    __shared__ float aoutL[NC];       // sigmoid(a_j)
    __shared__ float costL[NC];
    __shared__ float slogL[NC];
    __shared__ float msumL[NC];

    const int t = threadIdx.x;
    const int bid = blockIdx.x;           // b*144 + ho*12 + wo
    const int b = bid / 144;
    const int rem = bid - b * 144;
    const int ho = rem / 12;
    const int wo = rem - ho * 12;

    const int c = t & 31;
    const int rhalf = (t >> 5) & 1;
    const int isub = t >> 6;

    // ---- stage patch tile ----
    for (int idx = t; idx < KKI * 17; idx += NTHREADS) {
        int i = idx / 17;
        int e = idx - i * 17;
        int p = i >> 5, cin = i & 31;
        int di = p / 3, dj = p - di * 3;
        float vx = x[(((b * 14 + (ho + di)) * 14 + (wo + dj)) * 32 + cin) * 17 + e];
        if (e < 16) MpL[i * 16 + e] = vx; else apL[i] = vx;
    }
    for (int idx = t; idx < NC * 18; idx += NTHREADS) { T1L[idx] = 0.f; S1L[idx] = 0.f; S2L[idx] = 0.f; }
    if (t < NC) RsumL[t] = 0.f;
    __syncthreads();

    // stats part A: 512 threads, one (cap cc, dim dd) each; 16-lane d-group
    // shuffle reduce -> per-cap cost, slog, msum.
    auto statsA = [&]() {
        if (t < NC * 16) {
            int cc = t >> 4, dd = t & 15;
            float rsum = RsumL[cc];
            float inv_rsum = frcp(rsum);
            float m = T1L[cc * 18 + dd] * inv_rsum;
            float var = S2L[cc * 18 + dd] - 2.f * m * S1L[cc * 18 + dd] + 288.f * m * m;
            var = fmaxf(var, 0.f);
            float stdv = __fsqrt_rn(var);
            float lg = __logf(stdv + EPSF);
            float A = 0.5f * frcp(var);
            ML[cc * 18 + dd] = m;
            ABL[cc * 36 + dd * 2]     = A;
            ABL[cc * 36 + dd * 2 + 1] = 2.f * A * m;
            float ch = beta_v[cc] + lg;
            float sl = lg;
            float ms = A * m * m;
            ch += __shfl_xor(ch, 8); sl += __shfl_xor(sl, 8); ms += __shfl_xor(ms, 8);
            ch += __shfl_xor(ch, 4); sl += __shfl_xor(sl, 4); ms += __shfl_xor(ms, 4);
            ch += __shfl_xor(ch, 2); sl += __shfl_xor(sl, 2); ms += __shfl_xor(ms, 2);
            ch += __shfl_xor(ch, 1); sl += __shfl_xor(sl, 1); ms += __shfl_xor(ms, 1);
            if (dd == 0) { costL[cc] = ch * rsum; slogL[cc] = sl; msumL[cc] = ms; }
        }
    };
    // stats part B: 32 lanes, cross-cap mean/stdv -> a_j, constL, aoutL.
    auto statsB = [&](float inv_temp) {
        if (t < NC) {
            int cc = t;
            float cost = costL[cc];
            float csum = cost;
            csum += __shfl_xor(csum, 16); csum += __shfl_xor(csum, 8);
            csum += __shfl_xor(csum, 4);  csum += __shfl_xor(csum, 2);
            csum += __shfl_xor(csum, 1);
            float c_mean = csum * 0.03125f;
            float diff = cost - c_mean;
            float dsq = diff * diff;
            dsq += __shfl_xor(dsq, 16); dsq += __shfl_xor(dsq, 8);
            dsq += __shfl_xor(dsq, 4);  dsq += __shfl_xor(dsq, 2);
            dsq += __shfl_xor(dsq, 1);
            float c_stdv = __fsqrt_rn(dsq * 0.03125f);
            float a_cost = beta_a[cc] + (c_mean - cost) * frcp(c_stdv + EPSF);
            float a_j = frcp(1.f + __expf(-inv_temp * a_cost));
            constL[cc] = __logf(a_j + EPSF) - slogL[cc] - msumL[cc];
            aoutL[cc] = frcp(1.f + __expf(-a_j));
        }
    };

    // per-thread W base: row (i*32+c), columns rhalf*2+{0,1}; 4 float2 loads (q=0..3)
    const float* wbase = Wg + (size_t)((isub * IPT) * NC + c) * 16 + rhalf * 2;
    const int dbase = rhalf * 2;   // dd = p*4 + dbase + rr

    // ---- pass 0: R uniform 1/32; build T1, S1, S2 ----
    {
        float t1[8], s1[8], s2[8];
        #pragma unroll
        for (int ld = 0; ld < 8; ++ld) { t1[ld] = 0.f; s1[ld] = 0.f; s2[ld] = 0.f; }
        float rsum = 0.f;
        float2 w0, w1, w2, w3;   // W[q][dbase+{0,1}]
        {
            const float* wp = wbase;
            w0 = *(const float2*)(wp + 0); w1 = *(const float2*)(wp + 4);
            w2 = *(const float2*)(wp + 8); w3 = *(const float2*)(wp + 12);
        }
        for (int j = 0; j < IPT; ++j) {
            int i = isub * IPT + j;
            float a_i = apL[i];
            int jn = (j + 1 < IPT) ? j + 1 : j;
            const float* wpn = wbase + (size_t)jn * NC * 16;
            float2 nw0 = *(const float2*)(wpn + 0), nw1 = *(const float2*)(wpn + 4);
            float2 nw2 = *(const float2*)(wpn + 8), nw3 = *(const float2*)(wpn + 12);

            float rw = a_i * 0.03125f;
            rsum += rw;
            const float4* mp4 = (const float4*)(MpL + i * 16);
            #pragma unroll
            for (int p = 0; p < 4; ++p) {
                float4 mp = mp4[p];
                // rr = 0
                float v = mp.x * w0.x;
                v = fmaf(mp.y, w1.x, v); v = fmaf(mp.z, w2.x, v); v = fmaf(mp.w, w3.x, v);
                int ld = p * 2;
                t1[ld] = fmaf(rw, v, t1[ld]); s1[ld] += v; s2[ld] = fmaf(v, v, s2[ld]);
                // rr = 1
                float u = mp.x * w0.y;
                u = fmaf(mp.y, w1.y, u); u = fmaf(mp.z, w2.y, u); u = fmaf(mp.w, w3.y, u);
                ld = p * 2 + 1;
                t1[ld] = fmaf(rw, u, t1[ld]); s1[ld] += u; s2[ld] = fmaf(u, u, s2[ld]);
            }
            w0 = nw0; w1 = nw1; w2 = nw2; w3 = nw3;
        }
        if (rhalf == 0) atomicAdd(&RsumL[c], rsum);
        #pragma unroll
        for (int ld = 0; ld < 8; ++ld) {
            int dd = (ld >> 1) * 4 + dbase + (ld & 1);
            atomicAdd(&T1L[c * 18 + dd], t1[ld]);
            atomicAdd(&S1L[c * 18 + dd], s1[ld]);
            atomicAdd(&S2L[c * 18 + dd], s2[ld]);
        }
        __syncthreads();
        statsA();
        __syncthreads();
        statsB(1.0f);   // it = 0
        __syncthreads();
    }

    // ---- passes 1,2: fused E-step (softmax over c, in-register) + M-step ----
    for (int it = 1; it < 3; ++it) {
        for (int idx = t; idx < NC * 18; idx += NTHREADS) T1L[idx] = 0.f;
        if (t < NC) RsumL[t] = 0.f;
        __syncthreads();
        float Kc = constL[c];

        float t1[8];
        #pragma unroll
        for (int ld = 0; ld < 8; ++ld) t1[ld] = 0.f;
        float rsum = 0.f;
        float2 w0, w1, w2, w3;
        {
            const float* wp = wbase;
            w0 = *(const float2*)(wp + 0); w1 = *(const float2*)(wp + 4);
            w2 = *(const float2*)(wp + 8); w3 = *(const float2*)(wp + 12);
        }
        for (int j = 0; j < IPT; ++j) {
            int i = isub * IPT + j;
            float a_i = apL[i];
            int jn = (j + 1 < IPT) ? j + 1 : j;
            const float* wpn = wbase + (size_t)jn * NC * 16;
            float2 nw0 = *(const float2*)(wpn + 0), nw1 = *(const float2*)(wpn + 4);
            float2 nw2 = *(const float2*)(wpn + 8), nw3 = *(const float2*)(wpn + 12);

            const float4* mp4 = (const float4*)(MpL + i * 16);
            float v[8];
            float lp = 0.f;   // Kc added once after the cross-half combine
            #pragma unroll
            for (int p = 0; p < 4; ++p) {
                float4 mp = mp4[p];
                float vv = mp.x * w0.x;
                vv = fmaf(mp.y, w1.x, vv); vv = fmaf(mp.z, w2.x, vv); vv = fmaf(mp.w, w3.x, vv);
                v[p * 2] = vv;
                float uu = mp.x * w0.y;
                uu = fmaf(mp.y, w1.y, uu); uu = fmaf(mp.z, w2.y, uu); uu = fmaf(mp.w, w3.y, uu);
                v[p * 2 + 1] = uu;
                // AB: {A_dd, B_dd, A_dd+1, B_dd+1} at 16B-aligned offset
                float4 ab = *(const float4*)(ABL + c * 36 + 8 * p + 4 * rhalf);
                float tt = fmaf(-vv, ab.x, ab.y);   // B - A*v
                lp = fmaf(vv, tt, lp);
                float tu = fmaf(-uu, ab.z, ab.w);
                lp = fmaf(uu, tu, lp);
            }
            lp += __shfl_xor(lp, 32);   // combine the two rhalf halves
            lp += Kc;                   // per-cap constant, exactly once
            // softmax over the 32 caps in this half-wave
            float mx = lp;
            mx = fmaxf(mx, __shfl_xor(mx, 16)); mx = fmaxf(mx, __shfl_xor(mx, 8));
            mx = fmaxf(mx, __shfl_xor(mx, 4));  mx = fmaxf(mx, __shfl_xor(mx, 2));
            mx = fmaxf(mx, __shfl_xor(mx, 1));
            float ex = __expf(lp - mx);
            float s = ex;
            s += __shfl_xor(s, 16); s += __shfl_xor(s, 8);
            s += __shfl_xor(s, 4);  s += __shfl_xor(s, 2);
            s += __shfl_xor(s, 1);
            float r = ex * frcp(s);
            float rw = r * a_i;
            rsum += rw;
            #pragma unroll
            for (int ld = 0; ld < 8; ++ld) t1[ld] = fmaf(rw, v[ld], t1[ld]);
            w0 = nw0; w1 = nw1; w2 = nw2; w3 = nw3;
        }
        if (rhalf == 0) atomicAdd(&RsumL[c], rsum);
        #pragma unroll
        for (int ld = 0; ld < 8; ++ld) {
            int dd = (ld >> 1) * 4 + dbase + (ld & 1);
            atomicAdd(&T1L[c * 18 + dd], t1[ld]);
        }
        __syncthreads();
        statsA();
        __syncthreads();
        statsB(1.0f + (float)it);   // inv_temp = 1 + it
        __syncthreads();
    }

    // ---- epilogue ----
    for (int idx = t; idx < NC * 17; idx += NTHREADS) {
        int cc = idx / 17;
        int e = idx - cc * 17;
        float val = (e < 16) ? ML[cc * 18 + e] : aoutL[cc];
        out[(size_t)bid * (NC * 17) + idx] = val;
    }
}

extern "C" void kernel_launch(void* const* d_in, const int* in_sizes, int n_in,
                              void* d_out, int out_size, void* d_ws, size_t ws_size,
                              hipStream_t stream) {
    const float* x  = (const float*)d_in[0];
    const float* W  = (const float*)d_in[1];
    const float* bv = (const float*)d_in[2];
    const float* ba = (const float*)d_in[3];
    float* out = (float*)d_out;
    caps_em_kernel<<<288, NTHREADS, 0, stream>>>(x, W, bv, ba, out);
}